// Round 6
// baseline (60.699 us; speedup 1.0000x reference)
//
#include <hip/hip_runtime.h>

// Problem constants (match reference)
#define PP 32   // patches
#define SS 4
#define CC 64
#define HH 128
#define WW 128
#define NC 32   // channels kept per patch
#define OO 32   // adaptive pool output size (MIN_SIZE)
#define PLANE (HH * WW)

// ws: int cbase[PP*NC]; int psize[PP]
// cbase[p*NC+c] = element offset of crop origin in (p, s=0, channels[p][c])
__global__ __launch_bounds__(256) void setup_kernel(
    const int* __restrict__ size_raw,
    const int* __restrict__ pix,
    const int* __restrict__ channels,
    int*       __restrict__ cbase,   // [PP*NC]
    int*       __restrict__ psize)   // [PP]
{
    const int i = blockIdx.x * 256 + threadIdx.x;   // 0..1023
    const int p = i >> 5;
    const int c = i & 31;
    const int size = size_raw[p] + OO;              // [32,128]
    const int wr = WW - size + 1;
    const int hr = HH - size + 1;
    const int pm = pix[p] % (wr * hr);
    const int offy = pm / wr;
    const int offx = pm - offy * wr;
    if (c == 0) psize[p] = size;
    const int ch = channels[p * NC + c];
    cbase[i] = (p * SS * CC + ch) * PLANE + offy * WW + offx;
}

// One 256-thread block per (p,s,c) crop.
// Phase 1: halves (128 lanes) each own 16 o-bins; lane x sweeps the bin's
//          rows reading column x (contiguous coalesced row segments, each
//          crop row fetched once from DRAM; overlap rows are L1 hits).
//          Column sums staged in LDS [32][129] (bank-staggered).
// Phase 2: after ONE barrier, each thread produces 4 consecutive q outputs
//          (<=5 LDS reads each) and does one contiguous float4 store.
__global__ __launch_bounds__(256) void pool_kernel(
    const float* __restrict__ input,   // [P,S,C,H,W]
    const int*   __restrict__ cbase,   // [PP*NC]
    const int*   __restrict__ psize,   // [PP]
    float*       __restrict__ out)     // [P,S,NC,O,O]
{
    __shared__ float cs[OO][129];

    const int blk = blockIdx.x;        // (p<<7)|(s<<5)|c
    const int c = blk & (NC - 1);
    const int s = (blk >> 5) & (SS - 1);
    const int p = blk >> 7;
    const int t = threadIdx.x;
    const int x = t & 127;             // crop column owned by this lane
    const int h = t >> 7;              // o-half (0: o<16, 1: o>=16)

    const int size = psize[p];         // wave-uniform
    const float* base = input + cbase[(p << 5) | c] + s * (CC * PLANE);

    const int o0 = h << 4;
    #pragma unroll 1
    for (int oi = 0; oi < 16; ++oi) {
        const int o  = o0 + oi;
        const int sy = (o * size) >> 5;
        const int ey = ((o + 1) * size + 31) >> 5;
        float a = 0.0f;
        if (x < size) {
            const float* r = base + sy * WW + x;
            for (int y = sy; y < ey; ++y, r += WW) a += *r;
        }
        cs[o][x] = a;                  // lanes -> stride-1 cols: conflict-free
    }
    __syncthreads();

    // Phase 2: outputs i0..i0+3 of this block's 32x32 tile
    const int i0 = t << 2;
    const int q0 = i0 & (OO - 1);
    const int o  = i0 >> 5;
    const int rows = (((o + 1) * size + 31) >> 5) - ((o * size) >> 5);

    float acc[4];
    #pragma unroll
    for (int j = 0; j < 4; ++j) {
        const int q  = q0 + j;
        const int sx = (q * size) >> 5;
        const int ex = ((q + 1) * size + 31) >> 5;
        float a = 0.0f;
        for (int xx = sx; xx < ex; ++xx) a += cs[o][xx];
        acc[j] = a * __builtin_amdgcn_rcpf((float)(rows * (ex - sx)));
    }
    *(float4*)(out + ((size_t)blk << 10) + i0) =
        make_float4(acc[0], acc[1], acc[2], acc[3]);
}

extern "C" void kernel_launch(void* const* d_in, const int* in_sizes, int n_in,
                              void* d_out, int out_size, void* d_ws, size_t ws_size,
                              hipStream_t stream) {
    const float* input    = (const float*)d_in[0];
    const int*   size_raw = (const int*)d_in[1];
    const int*   pix      = (const int*)d_in[2];
    const int*   channels = (const int*)d_in[3];
    float*       out      = (float*)d_out;

    int* cbase = (int*)d_ws;            // 1024 ints
    int* psize = cbase + PP * NC;       // 32 ints

    setup_kernel<<<4, 256, 0, stream>>>(size_raw, pix, channels, cbase, psize);

    const int grid = PP * SS * NC;      // 4096 blocks
    pool_kernel<<<grid, 256, 0, stream>>>(input, cbase, psize, out);
}